// Round 5
// baseline (156.512 us; speedup 1.0000x reference)
//
#include <hip/hip_runtime.h>

#define IDX_BASE 16777216UL   // 4096*64*64
#define LOSS_IDX 17039360UL   // IDX_BASE + 4096*64

typedef float4 f4;

__device__ __forceinline__ void gload_lds16(const float* g, float* s) {
    __builtin_amdgcn_global_load_lds(
        (const __attribute__((address_space(1))) unsigned int*)g,
        (__attribute__((address_space(3))) unsigned int*)s, 16, 0, 0);
}

// ---- c2[m][k] = ||codebook[m][k]||^2 ----
__global__ __launch_bounds__(256) void pq_c2(const float* __restrict__ cb,
                                             float* __restrict__ c2) {
    int m = blockIdx.x, k = threadIdx.x;
    const f4* row = reinterpret_cast<const f4*>(cb + ((size_t)m * 256 + k) * 64);
    float s0 = 0.f, s1 = 0.f;
    #pragma unroll
    for (int i = 0; i < 16; i += 2) {
        f4 a = row[i], b = row[i + 1];
        s0 = fmaf(a.x,a.x,s0); s0 = fmaf(a.y,a.y,s0); s0 = fmaf(a.z,a.z,s0); s0 = fmaf(a.w,a.w,s0);
        s1 = fmaf(b.x,b.x,s1); s1 = fmaf(b.y,b.y,s1); s1 = fmaf(b.z,b.z,s1); s1 = fmaf(b.w,b.w,s1);
    }
    c2[m * 256 + k] = s0 + s1;
}

// 4-code chunk: issue next chunk's loads FIRST, then 8x4x4 FMAs on current.
#define CHUNK4(CUR, NXT, Q0, LQ, LCC)                                         \
    {                                                                          \
        _Pragma("unroll") for (int q = 0; q < 4; ++q)                          \
            NXT[q] = cbs[(LQ + q) * 256 + (LCC)];                              \
        _Pragma("unroll") for (int q = 0; q < 4; ++q) {                        \
            _Pragma("unroll") for (int p = 0; p < 8; ++p) {                    \
                acc[p][Q0 + q] = fmaf(zv[p].x, CUR[q].x, acc[p][Q0 + q]);      \
                acc[p][Q0 + q] = fmaf(zv[p].y, CUR[q].y, acc[p][Q0 + q]);      \
                acc[p][Q0 + q] = fmaf(zv[p].z, CUR[q].z, acc[p][Q0 + q]);      \
                acc[p][Q0 + q] = fmaf(zv[p].w, CUR[q].w, acc[p][Q0 + q]);      \
            }                                                                  \
        }                                                                      \
    }

// Last chunk of a jg: p-outer so zv[p] reloads (next jg) issue as each row finishes.
#define CHUNK4_Z(CUR, NXT, Q0, LQ, LCC, ZCN)                                   \
    {                                                                          \
        _Pragma("unroll") for (int q = 0; q < 4; ++q)                          \
            NXT[q] = cbs[(LQ + q) * 256 + (LCC)];                              \
        _Pragma("unroll") for (int p = 0; p < 8; ++p) {                        \
            _Pragma("unroll") for (int q = 0; q < 4; ++q) {                    \
                acc[p][Q0 + q] = fmaf(zv[p].x, CUR[q].x, acc[p][Q0 + q]);      \
                acc[p][Q0 + q] = fmaf(zv[p].y, CUR[q].y, acc[p][Q0 + q]);      \
                acc[p][Q0 + q] = fmaf(zv[p].z, CUR[q].z, acc[p][Q0 + q]);      \
                acc[p][Q0 + q] = fmaf(zv[p].w, CUR[q].w, acc[p][Q0 + q]);      \
            }                                                                  \
            zv[p] = zb[p * 16 + (ZCN)];                                        \
        }                                                                      \
    }

// Block = one m x 256 rows, 512 threads. Thread tile: 8 rows x 16 codes.
// LDS: cb 64KB (col ^ (k&15)) + z 64KB (col ^ ((r>>3)&7)), f4-granular swizzle.
__global__ __launch_bounds__(512, 2) void pq_main(
    const float* __restrict__ z, const float* __restrict__ cb,
    const float* __restrict__ c2ws,
    float* __restrict__ out, float* __restrict__ partial)
{
    __shared__ f4 sC[256 * 16];   // 64 KB
    __shared__ f4 sZ[256 * 16];   // 64 KB
    __shared__ int sBest[256];
    __shared__ float sW[8];

    const int tid   = threadIdx.x;
    const int bx    = blockIdx.x;
    const int m     = bx >> 4;          // 16 consecutive blocks share codebook m
    const int chunk = bx & 15;
    const int cg    = tid & 15;         // code group: codes q*16+cg
    const int rg    = tid >> 4;         // row group [0,32): rows rg*8..rg*8+7
    const int w     = tid >> 6;
    const int lane  = tid & 63;

    const float* __restrict__ cbm = cb + (size_t)m * (256 * 64);

    // prefetch c2 for this thread's 16 codes (in flight during staging)
    float c2r[16];
    #pragma unroll
    for (int q = 0; q < 16; ++q) c2r[q] = c2ws[m * 256 + q * 16 + cg];

    // ---- stage codebook: linear LDS rows, source col pre-swizzled ^ (k&15) ----
    #pragma unroll
    for (int i = 0; i < 8; ++i) {
        int k0   = w * 32 + i * 4;            // 4 rows per wave-instr
        int krow = k0 + (lane >> 4);
        int gcol = (lane & 15) ^ (krow & 15);
        gload_lds16(cbm + krow * 64 + gcol * 4, (float*)&sC[k0 * 16]);
    }
    // ---- stage z tile: rows b = chunk*256 + r, source col ^ ((r>>3)&7) ----
    #pragma unroll
    for (int i = 0; i < 8; ++i) {
        int r0   = w * 32 + i * 4;
        int grow = r0 + (lane >> 4);
        int gcol = (lane & 15) ^ ((grow >> 3) & 7);
        const float* src = z + ((size_t)(chunk * 256 + grow) * 64 + m) * 64 + gcol * 4;
        gload_lds16(src, (float*)&sZ[r0 * 16]);
    }
    __syncthreads();

    // ---- acc init: fold -0.5*c2 (argmax of S-0.5*c2 == argmin dist, exact) ----
    float acc[8][16];
    #pragma unroll
    for (int q = 0; q < 16; ++q) {
        float iv = -0.5f * c2r[q];
        #pragma unroll
        for (int p = 0; p < 8; ++p) acc[p][q] = iv;
    }

    const int zsw = rg & 7;                 // z swizzle const per thread
    const f4* zb  = &sZ[(rg * 8) * 16];
    const f4* cbs = &sC[cg * 16];           // code q*16+cg lives at f4-offset q*256 + cg*16

    // ---- software-pipelined main loop ----
    f4 zv[8], bufA[4], bufB[4];
    #pragma unroll
    for (int p = 0; p < 8; ++p) zv[p] = zb[p * 16 + zsw];          // jg=0
    #pragma unroll
    for (int q = 0; q < 4; ++q) bufA[q] = cbs[q * 256 + cg];       // jg=0 chunk0

    #pragma unroll 2
    for (int jg = 0; jg < 16; ++jg) {
        const int cc  = jg ^ cg;
        const int jn  = (jg + 1) & 15;       // jg=15 wraps: 12 redundant reads, uniform code
        const int ccn = jn ^ cg;
        const int zcn = jn ^ zsw;
        CHUNK4  (bufA, bufB, 0,  4,  cc)
        CHUNK4  (bufB, bufA, 4,  8,  cc)
        CHUNK4  (bufA, bufB, 8,  12, cc)
        CHUNK4_Z(bufB, bufA, 12, 0,  ccn, zcn)
    }

    // ---- per-thread argmax (q ascending => k ascending => first-min tiebreak) ----
    float bv[8]; int bk[8];
    #pragma unroll
    for (int p = 0; p < 8; ++p) { bv[p] = acc[p][0]; bk[p] = cg; }
    #pragma unroll
    for (int q = 1; q < 16; ++q) {
        #pragma unroll
        for (int p = 0; p < 8; ++p) {
            if (acc[p][q] > bv[p]) { bv[p] = acc[p][q]; bk[p] = q * 16 + cg; }
        }
    }
    // ---- reduce across 16 code-groups (shfl_xor stays within 16-lane group) ----
    #pragma unroll
    for (int off = 1; off < 16; off <<= 1) {
        #pragma unroll
        for (int p = 0; p < 8; ++p) {
            float ov = __shfl_xor(bv[p], off, 64);
            int   ok = __shfl_xor(bk[p], off, 64);
            if (ov > bv[p] || (ov == bv[p] && ok < bk[p])) { bv[p] = ov; bk[p] = ok; }
        }
    }
    if (cg == 0) {
        #pragma unroll
        for (int p = 0; p < 8; ++p) sBest[rg * 8 + p] = bk[p];
    }
    __syncthreads();

    // ---- outputs: quantized (exact global-codebook copy), index, loss partial ----
    float lsum = 0.f;
    {
        int row = tid >> 1;
        int h   = tid & 1;
        int k   = sBest[row];
        int b   = chunk * 256 + row;
        int rsw = (row >> 3) & 7;
        const f4* q4 = reinterpret_cast<const f4*>(cbm + (size_t)k * 64) + h * 8;
        f4*       o4 = reinterpret_cast<f4*>(out + ((size_t)b * 64 + m) * 64) + h * 8;
        float l0 = 0.f, l1 = 0.f;
        #pragma unroll
        for (int c = 0; c < 8; ++c) {
            f4 qv = q4[c];
            f4 zv2 = sZ[row * 16 + (((h << 3) + c) ^ rsw)];
            o4[c] = qv;
            float d0 = qv.x - zv2.x, d1 = qv.y - zv2.y, d2 = qv.z - zv2.z, d3 = qv.w - zv2.w;
            l0 = fmaf(d0, d0, l0); l1 = fmaf(d1, d1, l1);
            l0 = fmaf(d2, d2, l0); l1 = fmaf(d3, d3, l1);
        }
        lsum = l0 + l1;
    }
    if (tid < 256) {
        int b = chunk * 256 + tid;
        out[IDX_BASE + (size_t)b * 64 + m] = (float)sBest[tid];
    }
    #pragma unroll
    for (int off = 1; off < 64; off <<= 1) lsum += __shfl_xor(lsum, off, 64);
    if (lane == 0) sW[w] = lsum;
    __syncthreads();
    if (tid == 0) {
        float t = 0.f;
        #pragma unroll
        for (int i = 0; i < 8; ++i) t += sW[i];
        partial[bx] = t;
    }
}

// ---- deterministic final reduction of 1024 block partials -> q_loss ----
__global__ __launch_bounds__(256) void pq_loss(const float* __restrict__ partial,
                                               float* __restrict__ out)
{
    __shared__ float sW[4];
    float s = (partial[threadIdx.x]       + partial[threadIdx.x + 256])
            + (partial[threadIdx.x + 512] + partial[threadIdx.x + 768]);
    #pragma unroll
    for (int off = 1; off < 64; off <<= 1) s += __shfl_xor(s, off, 64);
    if ((threadIdx.x & 63) == 0) sW[threadIdx.x >> 6] = s;
    __syncthreads();
    if (threadIdx.x == 0)
        out[LOSS_IDX] = ((sW[0] + sW[1]) + (sW[2] + sW[3])) * (1.25f / 16777216.0f);
}

extern "C" void kernel_launch(void* const* d_in, const int* in_sizes, int n_in,
                              void* d_out, int out_size, void* d_ws, size_t ws_size,
                              hipStream_t stream) {
    const float* zp  = (const float*)d_in[0];
    const float* cbp = (const float*)d_in[1];
    float* outp = (float*)d_out;
    float* c2ws = (float*)d_ws;                  // 64*256 floats = 64 KB
    float* part = (float*)d_ws + 64 * 256;       // 1024 floats

    pq_c2  <<<dim3(64),   dim3(256), 0, stream>>>(cbp, c2ws);
    pq_main<<<dim3(1024), dim3(512), 0, stream>>>(zp, cbp, c2ws, outp, part);
    pq_loss<<<dim3(1),    dim3(256), 0, stream>>>(part, outp);
}

// Round 6
// 107.407 us; speedup vs baseline: 1.4572x; 1.4572x over previous
//
#include <hip/hip_runtime.h>

#define IDX_BASE 16777216UL   // 4096*64*64
#define LOSS_IDX 17039360UL   // IDX_BASE + 4096*64
#define EPS2 0.02f            // rescue window on (M1 - M2), score units; error bound ~1e-3

typedef float4 f4;
typedef _Float16 half8 __attribute__((ext_vector_type(8)));
typedef float f32x4 __attribute__((ext_vector_type(4)));

__device__ __forceinline__ void gload_lds16(const float* g, float* s) {
    __builtin_amdgcn_global_load_lds(
        (const __attribute__((address_space(1))) unsigned int*)g,
        (__attribute__((address_space(3))) unsigned int*)s, 16, 0, 0);
}

// ---- c2[m][k] = ||codebook[m][k]||^2 (fp32, same table rescue uses) ----
__global__ __launch_bounds__(256) void pq_c2(const float* __restrict__ cb,
                                             float* __restrict__ c2) {
    int m = blockIdx.x, k = threadIdx.x;
    const f4* row = reinterpret_cast<const f4*>(cb + ((size_t)m * 256 + k) * 64);
    float s0 = 0.f, s1 = 0.f;
    #pragma unroll
    for (int i = 0; i < 16; i += 2) {
        f4 a = row[i], b = row[i + 1];
        s0 = fmaf(a.x,a.x,s0); s0 = fmaf(a.y,a.y,s0); s0 = fmaf(a.z,a.z,s0); s0 = fmaf(a.w,a.w,s0);
        s1 = fmaf(b.x,b.x,s1); s1 = fmaf(b.y,b.y,s1); s1 = fmaf(b.z,b.z,s1); s1 = fmaf(b.w,b.w,s1);
    }
    c2[m * 256 + k] = s0 + s1;
}

// Block = one m x 128 rows, 256 threads (4 waves). Wave w owns codes w*64..w*64+63
// as f16 hi/lo A-fragments in registers; z staged fp32 in LDS (swizzled) and
// converted once to f16 hi/lo B-fragments. 24 MFMA per 16-row tile.
__global__ __launch_bounds__(256, 2) void pq_main(
    const float* __restrict__ z, const float* __restrict__ cb,
    const float* __restrict__ c2ws,
    float* __restrict__ out, float* __restrict__ partial)
{
    __shared__ f4    sZ4[128 * 16];        // 32 KB; sZ4[r*16+c4] = z[r][(c4^(r&7))*4..]
    __shared__ half8 sZfrag[8 * 2 * 2 * 64]; // 32 KB; [rt][s][v][lane]
    __shared__ float sM1[4 * 128];
    __shared__ float sM2[4 * 128];
    __shared__ int   sK [4 * 128];
    __shared__ int   sBest[128];
    __shared__ float sW[4];

    const int tid = threadIdx.x, bx = blockIdx.x;
    const int m = bx >> 5, chunk = bx & 31;     // 32 consecutive blocks share m
    const int w = tid >> 6, lane = tid & 63;
    const int lh = lane >> 4, l15 = lane & 15;

    const float* __restrict__ cbm = cb + (size_t)m * (256 * 64);
    const f4* cb4m = reinterpret_cast<const f4*>(cbm);

    // ---- stage z fp32 (pre-swizzled source -> linear LDS), fire DMA first ----
    #pragma unroll
    for (int i = 0; i < 8; ++i) {
        int unit = i * 256 + w * 64 + lane;
        int row = unit >> 4, c4 = unit & 15;
        int c4p = c4 ^ (row & 7);
        const float* src = z + ((size_t)(chunk * 128 + row) * 64 + m) * 64 + c4p * 4;
        gload_lds16(src, (float*)&sZ4[i * 256 + w * 64]);
    }

    // ---- A-fragments: wave's 64 codes, f16 hi/lo, consistent k-map (lh*8+e per s) ----
    half8 ah[4][2], al[4][2];
    #pragma unroll
    for (int t = 0; t < 4; ++t) {
        int code = (w * 4 + t) * 16 + l15;
        const float* crow = cbm + code * 64 + lh * 8;
        #pragma unroll
        for (int s = 0; s < 2; ++s) {
            f4 a = *reinterpret_cast<const f4*>(crow + s * 32);
            f4 b = *reinterpret_cast<const f4*>(crow + s * 32 + 4);
            float v[8] = {a.x, a.y, a.z, a.w, b.x, b.y, b.z, b.w};
            #pragma unroll
            for (int e = 0; e < 8; ++e) {
                _Float16 h = (_Float16)v[e];
                ah[t][s][e] = h;
                al[t][s][e] = (_Float16)(v[e] - (float)h);
            }
        }
    }
    // ---- c2 init per lane: k = w*64 + t*16 + lh*4 + r ----
    f32x4 c2i[4];
    #pragma unroll
    for (int t = 0; t < 4; ++t)
        #pragma unroll
        for (int r = 0; r < 4; ++r)
            c2i[t][r] = -0.5f * c2ws[m * 256 + w * 64 + t * 16 + lh * 4 + r];

    __syncthreads();   // z staged

    // ---- convert z tile to f16 hi/lo B-fragments (once per block) ----
    #pragma unroll
    for (int it = 0; it < 4; ++it) {
        int id = it * 256 + tid;          // (r, grp): dims grp*8..grp*8+7
        int r = id >> 3, grp = id & 7;
        int swz = r & 7;
        f4 a = sZ4[r * 16 + ((grp * 2)     ^ swz)];
        f4 b = sZ4[r * 16 + ((grp * 2 + 1) ^ swz)];
        float v[8] = {a.x, a.y, a.z, a.w, b.x, b.y, b.z, b.w};
        half8 hi, lo;
        #pragma unroll
        for (int e = 0; e < 8; ++e) {
            _Float16 h = (_Float16)v[e];
            hi[e] = h; lo[e] = (_Float16)(v[e] - (float)h);
        }
        int l    = (grp & 3) * 16 + (r & 15);
        int base = (((r >> 4) * 2 + (grp >> 2)) * 2) * 64 + l;
        sZfrag[base] = hi; sZfrag[base + 64] = lo;
    }
    __syncthreads();

    // ---- main: 8 row-tiles x (4 code-tiles x 6 MFMA) + per-lane top-2 ----
    #pragma unroll 1
    for (int rt = 0; rt < 8; ++rt) {
        const half8* zf = &sZfrag[rt * 256 + lane];
        half8 bh0 = zf[0], bl0 = zf[64], bh1 = zf[128], bl1 = zf[192];
        float m1 = -1e30f, m2 = -1e30f; int k16 = 0;
        #pragma unroll
        for (int t = 0; t < 4; ++t) {
            f32x4 acc = c2i[t];
            acc = __builtin_amdgcn_mfma_f32_16x16x32_f16(ah[t][0], bh0, acc, 0, 0, 0);
            acc = __builtin_amdgcn_mfma_f32_16x16x32_f16(ah[t][1], bh1, acc, 0, 0, 0);
            acc = __builtin_amdgcn_mfma_f32_16x16x32_f16(ah[t][0], bl0, acc, 0, 0, 0);
            acc = __builtin_amdgcn_mfma_f32_16x16x32_f16(ah[t][1], bl1, acc, 0, 0, 0);
            acc = __builtin_amdgcn_mfma_f32_16x16x32_f16(al[t][0], bh0, acc, 0, 0, 0);
            acc = __builtin_amdgcn_mfma_f32_16x16x32_f16(al[t][1], bh1, acc, 0, 0, 0);
            #pragma unroll
            for (int r = 0; r < 4; ++r) {
                float v = acc[r];
                m2 = fmaxf(m2, fminf(v, m1));      // classic top-2 update
                bool gt = v > m1;
                m1  = gt ? v : m1;
                k16 = gt ? (t * 16 + r) : k16;
            }
        }
        int kw = k16 + lh * 4;                     // k within wave's 64 codes
        #pragma unroll
        for (int off = 16; off <= 32; off <<= 1) { // merge the 4 lane-groups per row
            float om1 = __shfl_xor(m1, off, 64);
            float om2 = __shfl_xor(m2, off, 64);
            int   okw = __shfl_xor(kw, off, 64);
            m2 = fmaxf(fmaxf(m2, om2), fminf(m1, om1));
            bool better = (om1 > m1) || (om1 == m1 && okw < kw);
            m1 = better ? om1 : m1;
            kw = better ? okw : kw;
        }
        if (lane < 16) {
            int row = rt * 16 + lane;
            sM1[w * 128 + row] = m1;
            sM2[w * 128 + row] = m2;
            sK [w * 128 + row] = kw;
        }
    }
    __syncthreads();

    // ---- per-row merge across 4 waves; flag near-ties for exact rescue ----
    if (tid < 128) {
        float M1 = -1e30f, M2 = -1e30f; int K1 = 0;
        #pragma unroll
        for (int w2 = 0; w2 < 4; ++w2) {
            float v1 = sM1[w2 * 128 + tid];
            float v2 = sM2[w2 * 128 + tid];
            int   kk = w2 * 64 + sK[w2 * 128 + tid];
            M2 = fmaxf(fmaxf(M2, v2), fminf(M1, v1));
            bool better = v1 > M1;      // w ascending: ties keep smaller k
            M1 = better ? v1 : M1;
            K1 = better ? kk : K1;
        }
        sBest[tid] = (M1 - M2 < EPS2) ? -1 : K1;
    }
    __syncthreads();

    // ---- rescue (rare): exact fp32 rescan, identical arithmetic to the
    //      R4 kernel that passed (score = -0.5c2 + fmaf-chain dot, first-k tie) ----
    for (int row = w; row < 128; row += 4) {
        if (sBest[row] >= 0) continue;            // wave-uniform
        int swz = row & 7;
        float bs = -1e30f; int bk = 0;
        #pragma unroll 1
        for (int j = 0; j < 4; ++j) {
            int k = j * 64 + lane;
            float s = -0.5f * c2ws[m * 256 + k];
            #pragma unroll
            for (int d4 = 0; d4 < 16; ++d4) {
                f4 c  = cb4m[k * 16 + d4];
                f4 zz = sZ4[row * 16 + (d4 ^ swz)];
                s = fmaf(zz.x, c.x, s); s = fmaf(zz.y, c.y, s);
                s = fmaf(zz.z, c.z, s); s = fmaf(zz.w, c.w, s);
            }
            if (s > bs) { bs = s; bk = k; }
        }
        #pragma unroll
        for (int off = 1; off < 64; off <<= 1) {
            float ov = __shfl_xor(bs, off, 64);
            int   ok = __shfl_xor(bk, off, 64);
            if (ov > bs || (ov == bs && ok < bk)) { bs = ov; bk = ok; }
        }
        if (lane == 0) sBest[row] = bk;
    }
    __syncthreads();

    // ---- outputs: quantized (exact codebook copy), index, loss partial ----
    float lsum = 0.f;
    {
        int row = tid >> 1, h = tid & 1;
        int k = sBest[row];
        int b = chunk * 128 + row;
        int swz = row & 7;
        const f4* q4 = cb4m + (size_t)k * 16 + h * 8;
        f4*       o4 = reinterpret_cast<f4*>(out + ((size_t)b * 64 + m) * 64) + h * 8;
        float l0 = 0.f, l1 = 0.f;
        #pragma unroll
        for (int c = 0; c < 8; ++c) {
            f4 qv = q4[c];
            f4 zv = sZ4[row * 16 + (((h << 3) + c) ^ swz)];
            o4[c] = qv;
            float d0 = qv.x - zv.x, d1 = qv.y - zv.y, d2 = qv.z - zv.z, d3 = qv.w - zv.w;
            l0 = fmaf(d0, d0, l0); l1 = fmaf(d1, d1, l1);
            l0 = fmaf(d2, d2, l0); l1 = fmaf(d3, d3, l1);
        }
        lsum = l0 + l1;
    }
    if (tid < 128)
        out[IDX_BASE + (size_t)(chunk * 128 + tid) * 64 + m] = (float)sBest[tid];
    #pragma unroll
    for (int off = 1; off < 64; off <<= 1) lsum += __shfl_xor(lsum, off, 64);
    if (lane == 0) sW[w] = lsum;
    __syncthreads();
    if (tid == 0) partial[bx] = (sW[0] + sW[1]) + (sW[2] + sW[3]);
}

// ---- deterministic final reduction of 2048 block partials -> q_loss ----
__global__ __launch_bounds__(256) void pq_loss(const float* __restrict__ partial,
                                               float* __restrict__ out)
{
    __shared__ float sW[4];
    float s = 0.f;
    #pragma unroll
    for (int i = 0; i < 8; ++i) s += partial[threadIdx.x + i * 256];
    #pragma unroll
    for (int off = 1; off < 64; off <<= 1) s += __shfl_xor(s, off, 64);
    if ((threadIdx.x & 63) == 0) sW[threadIdx.x >> 6] = s;
    __syncthreads();
    if (threadIdx.x == 0)
        out[LOSS_IDX] = ((sW[0] + sW[1]) + (sW[2] + sW[3])) * (1.25f / 16777216.0f);
}

extern "C" void kernel_launch(void* const* d_in, const int* in_sizes, int n_in,
                              void* d_out, int out_size, void* d_ws, size_t ws_size,
                              hipStream_t stream) {
    const float* zp  = (const float*)d_in[0];
    const float* cbp = (const float*)d_in[1];
    float* outp = (float*)d_out;
    float* c2ws = (float*)d_ws;                  // 64*256 floats = 64 KB
    float* part = (float*)d_ws + 64 * 256;       // 2048 floats

    pq_c2  <<<dim3(64),   dim3(256), 0, stream>>>(cbp, c2ws);
    pq_main<<<dim3(2048), dim3(256), 0, stream>>>(zp, cbp, c2ws, outp, part);
    pq_loss<<<dim3(1),    dim3(256), 0, stream>>>(part, outp);
}

// Round 7
// 93.043 us; speedup vs baseline: 1.6822x; 1.1544x over previous
//
#include <hip/hip_runtime.h>

#define IDX_BASE 16777216UL   // 4096*64*64
#define LOSS_IDX 17039360UL   // IDX_BASE + 4096*64
#define EPS2 0.02f            // rescue window on (M1 - M2); score err bound ~1e-3

typedef float4 f4;
typedef _Float16 half8 __attribute__((ext_vector_type(8)));
typedef float f32x4 __attribute__((ext_vector_type(4)));

__device__ __forceinline__ void gload_lds16(const float* g, float* s) {
    __builtin_amdgcn_global_load_lds(
        (const __attribute__((address_space(1))) unsigned int*)g,
        (__attribute__((address_space(3))) unsigned int*)s, 16, 0, 0);
}

// ---- c2[m][k] = ||codebook[m][k]||^2 (fp32, same table rescue uses) ----
__global__ __launch_bounds__(256) void pq_c2(const float* __restrict__ cb,
                                             float* __restrict__ c2) {
    int m = blockIdx.x, k = threadIdx.x;
    const f4* row = reinterpret_cast<const f4*>(cb + ((size_t)m * 256 + k) * 64);
    float s0 = 0.f, s1 = 0.f;
    #pragma unroll
    for (int i = 0; i < 16; i += 2) {
        f4 a = row[i], b = row[i + 1];
        s0 = fmaf(a.x,a.x,s0); s0 = fmaf(a.y,a.y,s0); s0 = fmaf(a.z,a.z,s0); s0 = fmaf(a.w,a.w,s0);
        s1 = fmaf(b.x,b.x,s1); s1 = fmaf(b.y,b.y,s1); s1 = fmaf(b.z,b.z,s1); s1 = fmaf(b.w,b.w,s1);
    }
    c2[m * 256 + k] = s0 + s1;
}

// Block = one m x 128 rows, 256 threads (4 waves). Wave w owns codes w*64..+63 as
// f16 hi/lo A-fragments in registers; z staged fp32 in LDS (swizzled); B-fragments
// converted on the fly per row-tile. LDS 39.4 KB -> 4 blocks/CU.
__global__ __launch_bounds__(256, 4) void pq_main(
    const float* __restrict__ z, const float* __restrict__ cb,
    const float* __restrict__ c2ws,
    float* __restrict__ out, float* __restrict__ partial)
{
    __shared__ f4    sZ4[128 * 16];   // 32 KB; sZ4[r*16+c4] = z[r][(c4^(r&7))*4..]
    __shared__ float sM1[4 * 128];
    __shared__ float sM2[4 * 128];
    __shared__ int   sK [4 * 128];
    __shared__ int   sBest[128];
    __shared__ float sW[4];

    const int tid = threadIdx.x, bx = blockIdx.x;
    const int m = bx >> 5, chunk = bx & 31;     // 32 consecutive blocks share m
    const int w = tid >> 6, lane = tid & 63;
    const int lh = lane >> 4, l15 = lane & 15;

    const float* __restrict__ cbm = cb + (size_t)m * (256 * 64);
    const f4* cb4m = reinterpret_cast<const f4*>(cbm);

    // ---- stage z fp32 (pre-swizzled source -> linear LDS), fire DMA first ----
    #pragma unroll
    for (int i = 0; i < 8; ++i) {
        int unit = i * 256 + w * 64 + lane;
        int row = unit >> 4, c4 = unit & 15;
        int c4p = c4 ^ (row & 7);
        const float* src = z + ((size_t)(chunk * 128 + row) * 64 + m) * 64 + c4p * 4;
        gload_lds16(src, (float*)&sZ4[i * 256 + w * 64]);
    }

    // ---- A-fragments: wave's 64 codes, f16 hi/lo, k-map (lh*8+e per s) ----
    half8 ah[4][2], al[4][2];
    #pragma unroll
    for (int t = 0; t < 4; ++t) {
        int code = (w * 4 + t) * 16 + l15;
        const float* crow = cbm + code * 64 + lh * 8;
        #pragma unroll
        for (int s = 0; s < 2; ++s) {
            f4 a = *reinterpret_cast<const f4*>(crow + s * 32);
            f4 b = *reinterpret_cast<const f4*>(crow + s * 32 + 4);
            float v[8] = {a.x, a.y, a.z, a.w, b.x, b.y, b.z, b.w};
            #pragma unroll
            for (int e = 0; e < 8; ++e) {
                _Float16 h = (_Float16)v[e];
                ah[t][s][e] = h;
                al[t][s][e] = (_Float16)(v[e] - (float)h);
            }
        }
    }
    // ---- c2 init per lane: k = w*64 + t*16 + lh*4 + r ----
    f32x4 c2i[4];
    #pragma unroll
    for (int t = 0; t < 4; ++t)
        #pragma unroll
        for (int r = 0; r < 4; ++r)
            c2i[t][r] = -0.5f * c2ws[m * 256 + w * 64 + t * 16 + lh * 4 + r];

    __syncthreads();   // z staged

    // ---- main: 8 row-tiles x {on-the-fly B-frag convert + 4x6 MFMA + top-2} ----
    #pragma unroll 1
    for (int rt = 0; rt < 8; ++rt) {
        // B-frags from sZ4: lane holds row rt*16+l15, dims lh*8..+8 (v0) / 32+lh*8..+8 (v1)
        const int row = rt * 16 + l15;
        const int swz = row & 7;
        const f4* zr = &sZ4[row * 16];
        const int c0 = lh << 1;
        f4 a0 = zr[(c0)     ^ swz];
        f4 a1 = zr[(c0 + 1) ^ swz];
        f4 a2 = zr[(c0 + 8) ^ swz];
        f4 a3 = zr[(c0 + 9) ^ swz];
        half8 bh0, bl0, bh1, bl1;
        {
            float v0[8] = {a0.x, a0.y, a0.z, a0.w, a1.x, a1.y, a1.z, a1.w};
            float v1[8] = {a2.x, a2.y, a2.z, a2.w, a3.x, a3.y, a3.z, a3.w};
            #pragma unroll
            for (int e = 0; e < 8; ++e) {
                _Float16 h0 = (_Float16)v0[e];
                bh0[e] = h0; bl0[e] = (_Float16)(v0[e] - (float)h0);
                _Float16 h1 = (_Float16)v1[e];
                bh1[e] = h1; bl1[e] = (_Float16)(v1[e] - (float)h1);
            }
        }
        float m1 = -1e30f, m2 = -1e30f; int k16 = 0;
        #pragma unroll
        for (int t = 0; t < 4; ++t) {
            f32x4 acc = c2i[t];
            acc = __builtin_amdgcn_mfma_f32_16x16x32_f16(ah[t][0], bh0, acc, 0, 0, 0);
            acc = __builtin_amdgcn_mfma_f32_16x16x32_f16(ah[t][1], bh1, acc, 0, 0, 0);
            acc = __builtin_amdgcn_mfma_f32_16x16x32_f16(ah[t][0], bl0, acc, 0, 0, 0);
            acc = __builtin_amdgcn_mfma_f32_16x16x32_f16(ah[t][1], bl1, acc, 0, 0, 0);
            acc = __builtin_amdgcn_mfma_f32_16x16x32_f16(al[t][0], bh0, acc, 0, 0, 0);
            acc = __builtin_amdgcn_mfma_f32_16x16x32_f16(al[t][1], bh1, acc, 0, 0, 0);
            #pragma unroll
            for (int r = 0; r < 4; ++r) {
                float v = acc[r];
                m2 = fmaxf(m2, fminf(v, m1));      // classic top-2 update
                bool gt = v > m1;
                m1  = gt ? v : m1;
                k16 = gt ? (t * 16 + r) : k16;
            }
        }
        int kw = k16 + lh * 4;                     // k within wave's 64 codes
        #pragma unroll
        for (int off = 16; off <= 32; off <<= 1) { // merge the 4 lane-groups per row
            float om1 = __shfl_xor(m1, off, 64);
            float om2 = __shfl_xor(m2, off, 64);
            int   okw = __shfl_xor(kw, off, 64);
            m2 = fmaxf(fmaxf(m2, om2), fminf(m1, om1));
            bool better = (om1 > m1) || (om1 == m1 && okw < kw);
            m1 = better ? om1 : m1;
            kw = better ? okw : kw;
        }
        if (lane < 16) {
            int r2 = rt * 16 + lane;
            sM1[w * 128 + r2] = m1;
            sM2[w * 128 + r2] = m2;
            sK [w * 128 + r2] = kw;
        }
    }
    __syncthreads();

    // ---- per-row merge across 4 waves; flag near-ties for exact rescue ----
    if (tid < 128) {
        float M1 = -1e30f, M2 = -1e30f; int K1 = 0;
        #pragma unroll
        for (int w2 = 0; w2 < 4; ++w2) {
            float v1 = sM1[w2 * 128 + tid];
            float v2 = sM2[w2 * 128 + tid];
            int   kk = w2 * 64 + sK[w2 * 128 + tid];
            M2 = fmaxf(fmaxf(M2, v2), fminf(M1, v1));
            bool better = v1 > M1;      // w ascending: ties keep smaller k
            M1 = better ? v1 : M1;
            K1 = better ? kk : K1;
        }
        sBest[tid] = (M1 - M2 < EPS2) ? -1 : K1;
    }
    __syncthreads();

    // ---- rescue (rare): exact fp32 rescan, identical arithmetic to the
    //      validated R4 kernel (score = -0.5c2 + fmaf dot, first-k tie) ----
    for (int row = w; row < 128; row += 4) {
        if (sBest[row] >= 0) continue;            // wave-uniform
        int swz = row & 7;
        float bs = -1e30f; int bk = 0;
        #pragma unroll 1
        for (int j = 0; j < 4; ++j) {
            int k = j * 64 + lane;
            float s = -0.5f * c2ws[m * 256 + k];
            #pragma unroll
            for (int d4 = 0; d4 < 16; ++d4) {
                f4 c  = cb4m[k * 16 + d4];
                f4 zz = sZ4[row * 16 + (d4 ^ swz)];
                s = fmaf(zz.x, c.x, s); s = fmaf(zz.y, c.y, s);
                s = fmaf(zz.z, c.z, s); s = fmaf(zz.w, c.w, s);
            }
            if (s > bs) { bs = s; bk = k; }
        }
        #pragma unroll
        for (int off = 1; off < 64; off <<= 1) {
            float ov = __shfl_xor(bs, off, 64);
            int   ok = __shfl_xor(bk, off, 64);
            if (ov > bs || (ov == bs && ok < bk)) { bs = ov; bk = ok; }
        }
        if (lane == 0) sBest[row] = bk;
    }
    __syncthreads();

    // ---- outputs: quantized (exact codebook copy), index, loss partial ----
    float lsum = 0.f;
    {
        int row = tid >> 1, h = tid & 1;
        int k = sBest[row];
        int b = chunk * 128 + row;
        int swz = row & 7;
        const f4* q4 = cb4m + (size_t)k * 16 + h * 8;
        f4*       o4 = reinterpret_cast<f4*>(out + ((size_t)b * 64 + m) * 64) + h * 8;
        float l0 = 0.f, l1 = 0.f;
        #pragma unroll
        for (int c = 0; c < 8; ++c) {
            f4 qv = q4[c];
            f4 zv = sZ4[row * 16 + (((h << 3) + c) ^ swz)];
            o4[c] = qv;
            float d0 = qv.x - zv.x, d1 = qv.y - zv.y, d2 = qv.z - zv.z, d3 = qv.w - zv.w;
            l0 = fmaf(d0, d0, l0); l1 = fmaf(d1, d1, l1);
            l0 = fmaf(d2, d2, l0); l1 = fmaf(d3, d3, l1);
        }
        lsum = l0 + l1;
    }
    if (tid < 128)
        out[IDX_BASE + (size_t)(chunk * 128 + tid) * 64 + m] = (float)sBest[tid];
    #pragma unroll
    for (int off = 1; off < 64; off <<= 1) lsum += __shfl_xor(lsum, off, 64);
    if (lane == 0) sW[w] = lsum;
    __syncthreads();
    if (tid == 0) partial[bx] = (sW[0] + sW[1]) + (sW[2] + sW[3]);
}

// ---- deterministic final reduction of 2048 block partials -> q_loss ----
__global__ __launch_bounds__(256) void pq_loss(const float* __restrict__ partial,
                                               float* __restrict__ out)
{
    __shared__ float sW[4];
    float s = 0.f;
    #pragma unroll
    for (int i = 0; i < 8; ++i) s += partial[threadIdx.x + i * 256];
    #pragma unroll
    for (int off = 1; off < 64; off <<= 1) s += __shfl_xor(s, off, 64);
    if ((threadIdx.x & 63) == 0) sW[threadIdx.x >> 6] = s;
    __syncthreads();
    if (threadIdx.x == 0)
        out[LOSS_IDX] = ((sW[0] + sW[1]) + (sW[2] + sW[3])) * (1.25f / 16777216.0f);
}

extern "C" void kernel_launch(void* const* d_in, const int* in_sizes, int n_in,
                              void* d_out, int out_size, void* d_ws, size_t ws_size,
                              hipStream_t stream) {
    const float* zp  = (const float*)d_in[0];
    const float* cbp = (const float*)d_in[1];
    float* outp = (float*)d_out;
    float* c2ws = (float*)d_ws;                  // 64*256 floats = 64 KB
    float* part = (float*)d_ws + 64 * 256;       // 2048 floats

    pq_c2  <<<dim3(64),   dim3(256), 0, stream>>>(cbp, c2ws);
    pq_main<<<dim3(2048), dim3(256), 0, stream>>>(zp, cbp, c2ws, outp, part);
    pq_loss<<<dim3(1),    dim3(256), 0, stream>>>(part, outp);
}